// Round 11
// baseline (103.786 us; speedup 1.0000x reference)
//
#include <hip/hip_runtime.h>
#include <hip/hip_bf16.h>

#define NUM_AGES 100
#define FEAT 512
#define BATCH 4096
#define EPSF 1e-6f
#define INV_T 10.0f
#define INV_NORM (1.0f / ((float)BATCH * (float)(BATCH - 1)))

#define BM 256
#define BN 256
#define BK 64
// kept tiles: by <= bx, bx in [0,16) -> 16*17/2 = 136 = 8*17 (bijective XCD chunking)
#define NTILES 136

typedef __bf16 bf16_t;
typedef __bf16 v8bf __attribute__((ext_vector_type(8)));
typedef float v4f __attribute__((ext_vector_type(4)));

// async global->LDS, 16B per lane; LDS dest is wave-uniform base + lane*16
__device__ __forceinline__ void async16(const void* g, void* l) {
  __builtin_amdgcn_global_load_lds(
      (const __attribute__((address_space(1))) void*)g,
      (__attribute__((address_space(3))) void*)l, 16, 0, 0);
}

// ---------------- kernel 1: prep (samples + U table) — v10, passed -------
// Factorization: w_j depends only on age a_j (100 distinct w vectors);
// H[i,j] = ZU[i, a_j], ZU = Z @ U^T. Blocks 0..511: one wave per sample
// (rank scan via LDS int4, butterfly reduce, pre-swizzled bf16 z store).
// Blocks 512..527: U-table rows (128 padded, pre-swizzled by a&7).
__global__ __launch_bounds__(512) void prep_kernel(
    const float* __restrict__ z, const int* __restrict__ ages,
    const float* __restrict__ proxies,
    bf16_t* __restrict__ zb, bf16_t* __restrict__ ub,
    float* __restrict__ sq, int* __restrict__ ages_s, float* __restrict__ out)
{
  int t = threadIdx.x;
  int wv = t >> 6, lane = t & 63;

  if (blockIdx.x >= 512) {
    int a = (blockIdx.x - 512) * 8 + wv;   // 0..127
    int c0 = lane * 8;
    union { bf16_t h[8]; uint4 u; } uw;
    if (a < NUM_AGES) {
      int an = a + 1 > NUM_AGES - 1 ? NUM_AGES - 1 : a + 1;
      int ap = a - 1 < 0 ? 0 : a - 1;
      const float4* cc4 = (const float4*)(proxies + (size_t)a  * FEAT + c0);
      const float4* cn4 = (const float4*)(proxies + (size_t)an * FEAT + c0);
      const float4* cp4 = (const float4*)(proxies + (size_t)ap * FEAT + c0);
      float df[8], db[8];
      float ff = 0.f, bb = 0.f;
#pragma unroll
      for (int h = 0; h < 2; ++h) {
        float4 c4 = cc4[h], n4 = cn4[h], p4 = cp4[h];
        float cA[4] = {c4.x, c4.y, c4.z, c4.w};
        float nA[4] = {n4.x, n4.y, n4.z, n4.w};
        float pA[4] = {p4.x, p4.y, p4.z, p4.w};
#pragma unroll
        for (int i2 = 0; i2 < 4; ++i2) {
          int i = h * 4 + i2;
          df[i] = nA[i2] - cA[i2];
          db[i] = pA[i2] - cA[i2];
          ff += df[i] * df[i];
          bb += db[i] * db[i];
        }
      }
#pragma unroll
      for (int off = 32; off > 0; off >>= 1) {
        ff += __shfl_xor(ff, off, 64);
        bb += __shfl_xor(bb, off, 64);
      }
      float rf = 1.0f / (sqrtf(ff) + EPSF);
      float rb = 1.0f / (sqrtf(bb) + EPSF);
#pragma unroll
      for (int i = 0; i < 8; ++i)
        uw.h[i] = (bf16_t)(db[i] * rb - df[i] * rf);
    } else {
      uw.u = (uint4){0u, 0u, 0u, 0u};
    }
    int key = a & 7;
    int c2s = (c0 & ~63) | ((((c0 >> 3) & 7) ^ key) << 3);
    *(uint4*)((char*)ub + ((size_t)a * FEAT + c2s) * 2) = uw.u;
    return;
  }

  __shared__ __attribute__((aligned(16))) int sa[BATCH];   // 16 KB
  if (blockIdx.x == 0 && t == 0) out[0] = 0.0f;   // pair accumulates into out

  ((int4*)sa)[t]       = ((const int4*)ages)[t];
  ((int4*)sa)[t + 512] = ((const int4*)ages)[t + 512];
  __syncthreads();

  int j = blockIdx.x * 8 + wv;
  int araw = sa[j];

  int cnt = 0;
  const int4* sa4 = (const int4*)sa;
#pragma unroll
  for (int e = 0; e < 16; ++e) {
    int idx = lane + 64 * e;
    int4 v = sa4[idx];
    int k = idx * 4;
    cnt += (v.x < araw || (v.x == araw && k     < j)) ? 1 : 0;
    cnt += (v.y < araw || (v.y == araw && k + 1 < j)) ? 1 : 0;
    cnt += (v.z < araw || (v.z == araw && k + 2 < j)) ? 1 : 0;
    cnt += (v.w < araw || (v.w == araw && k + 3 < j)) ? 1 : 0;
  }

  int c0 = lane * 8;
  const float4* zr4 = (const float4*)(z + (size_t)j * FEAT + c0);
  float zv[8];
  float zz = 0.f;
#pragma unroll
  for (int h = 0; h < 2; ++h) {
    float4 z4 = zr4[h];
    float zA[4] = {z4.x, z4.y, z4.z, z4.w};
#pragma unroll
    for (int i2 = 0; i2 < 4; ++i2) {
      zv[h * 4 + i2] = zA[i2];
      zz += zA[i2] * zA[i2];
    }
  }
#pragma unroll
  for (int off = 32; off > 0; off >>= 1) {
    zz  += __shfl_xor(zz,  off, 64);
    cnt += __shfl_xor(cnt, off, 64);
  }
  int rank = cnt;
  int key = rank & 7;
  int c2s = (c0 & ~63) | ((((c0 >> 3) & 7) ^ key) << 3);

  union { bf16_t h[8]; uint4 u; } uz;
#pragma unroll
  for (int i = 0; i < 8; ++i) uz.h[i] = (bf16_t)zv[i];
  *(uint4*)((char*)zb + ((size_t)rank * FEAT + c2s) * 2) = uz.u;
  if (lane == 0) {
    sq[rank] = zz;
    ages_s[rank] = araw;
  }
}

// ---------------- kernel 2: ZU = Zsorted @ U^T (32 blocks) — v10, passed -
__global__ __launch_bounds__(256, 3) void zu_kernel(
    const bf16_t* __restrict__ zb, const bf16_t* __restrict__ ub,
    float* __restrict__ zut)
{
  __shared__ __attribute__((aligned(16))) char lds[32768];
  int t = threadIdx.x;
  int wv = t >> 6, lane = t & 63;
  int r0 = blockIdx.x * 128;

  v4f acc[4][4];
#pragma unroll
  for (int a = 0; a < 4; ++a)
#pragma unroll
    for (int b = 0; b < 4; ++b) acc[a][b] = (v4f){0.f, 0.f, 0.f, 0.f};

  int wm = wv >> 1, wn = wv & 1;
  int lm = lane & 15, q = lane >> 4;
  int psw0 = ((q    ) ^ (lm & 7)) * 16;
  int psw1 = ((q + 4) ^ (lm & 7)) * 16;
  int loff = (lane >> 3) * FEAT + (lane & 7) * 8;
  const bf16_t* baseA = zb + (size_t)r0 * FEAT + loff;
  const bf16_t* baseU = ub + loff;

  for (int k0 = 0; k0 < FEAT; k0 += BK) {
#pragma unroll
    for (int c = 0; c < 4; ++c) {
      int chunk = wv * 4 + c;
      async16(baseA + (size_t)chunk * 8 * FEAT + k0, lds + chunk * 1024);
      async16(baseU + (size_t)chunk * 8 * FEAT + k0, lds + 16384 + chunk * 1024);
    }
    __syncthreads();
#pragma unroll
    for (int s = 0; s < 2; ++s) {
      int psw = s ? psw1 : psw0;
      v8bf afr[4], bu[4];
#pragma unroll
      for (int mi = 0; mi < 4; ++mi) {
        int r = wm * 64 + mi * 16 + lm;
        afr[mi] = *(const v8bf*)(lds + r * 128 + psw);
      }
#pragma unroll
      for (int ni = 0; ni < 4; ++ni) {
        int r = wn * 64 + ni * 16 + lm;
        bu[ni] = *(const v8bf*)(lds + 16384 + r * 128 + psw);
      }
#pragma unroll
      for (int mi = 0; mi < 4; ++mi)
#pragma unroll
        for (int ni = 0; ni < 4; ++ni)
          acc[mi][ni] = __builtin_amdgcn_mfma_f32_16x16x32_bf16(afr[mi], bu[ni], acc[mi][ni], 0, 0, 0);
    }
    __syncthreads();
  }

#pragma unroll
  for (int ni = 0; ni < 4; ++ni) {
    int age = wn * 64 + ni * 16 + lm;
#pragma unroll
    for (int mi = 0; mi < 4; ++mi) {
      int rb0 = r0 + wm * 64 + mi * 16 + q * 4;
      *(v4f*)(zut + (size_t)age * BATCH + rb0) = acc[mi][ni];
    }
  }
}

// ---------------- kernel 3: pairwise G-GEMM (v11: 256x256 tile) ----------
// v10 evidence: pair invariant ~40-46us across schedules at 128x128; staged
// bytes cut 203->135MB gave only ~3-5us -> mixed aggregate-BW/per-CU regime.
// v11 quarters per-output staging with BM=BN=256: 136 tiles x 512KB = 70MB
// total (0.5x v10); 136 = 8x17 bijective XCD chunk; <=1 block/CU -> ZERO
// straggler tail (v10: 2.06 blocks/CU). 8 waves 2x4, per-wave 128x64:
// acc[8][4] = 128 AGPR + ~75 VGPR ~= 205 <= 256 cap (launch_bounds(512,2)).
// Double-buffered LDS 2x64KB (v6-verified plain pattern: STAGE(t+1) ->
// compute buf[cur] -> one __syncthreads) -- mandatory at 1 block/CU since
// no other block hides the drain. ds_read:MFMA per wave-phase = 12:32.
__global__ __launch_bounds__(512, 2) void pair_kernel(
    const bf16_t* __restrict__ zb, const float* __restrict__ zut,
    const float* __restrict__ sq, const int* __restrict__ ages,
    float* __restrict__ out)
{
  // per buffer: A 256x64 bf16 = 32768 B | Z 256x64 bf16 = 32768 B
  __shared__ __attribute__((aligned(16))) char lds[2][65536];
  __shared__ float s_sqi[BM];
  __shared__ int   s_agei[BM];
  __shared__ float s_sqj[BN];
  __shared__ float s_hdj[BN];
  __shared__ int   s_agej[BN];
  __shared__ float wsum[8];

  int t = threadIdx.x;
  int wv = t >> 6, lane = t & 63;

  // ---- tile decode: XCD chunk + column-major triangle (by <= bx) ----
  int id = (blockIdx.x & 7) * (NTILES / 8) + (blockIdx.x >> 3);
  int bx = 0, rem = id;
  while (rem >= bx + 1) { rem -= bx + 1; ++bx; }
  int by = rem;
  int i0 = by * BM, j0 = bx * BN;

  int wm = wv >> 2, wn = wv & 3;        // wave grid 2x4: 128 rows x 64 cols each
  int lm = lane & 15, q = lane >> 4;
  int psw0 = ((q    ) ^ (lm & 7)) * 16;
  int psw1 = ((q + 4) ^ (lm & 7)) * 16;

  int loff = (lane >> 3) * FEAT + (lane & 7) * 8;
  const bf16_t* baseA = zb + (size_t)i0 * FEAT + loff;
  const bf16_t* baseZ = zb + (size_t)j0 * FEAT + loff;

  // stage one K-tile: 32 A-chunks + 32 Z-chunks of 8 rows; wave wv does 4+4
  auto STAGE = [&](int k0, char* nb) {
#pragma unroll
    for (int c = 0; c < 4; ++c) {
      int chunk = wv * 4 + c;
      async16(baseA + (size_t)chunk * 8 * FEAT + k0, nb + chunk * 1024);
      async16(baseZ + (size_t)chunk * 8 * FEAT + k0, nb + 32768 + chunk * 1024);
    }
  };

  // ---- prologue: stage tile 0; aux loads overlap the drain ----
  STAGE(0, lds[0]);

  if (t < BM) {
    s_sqi[t] = sq[i0 + t];
    s_agei[t] = ages[i0 + t];
  } else {
    int u = t - BM;   // u in [0,256)
    int raw = ages[j0 + u];
    int ac = raw < 0 ? 0 : (raw > NUM_AGES - 1 ? NUM_AGES - 1 : raw);
    s_sqj[u] = sq[j0 + u];
    s_agej[u] = raw;
    s_hdj[u] = zut[(size_t)ac * BATCH + j0 + u];
  }

  v4f accG[8][4];
#pragma unroll
  for (int a = 0; a < 8; ++a)
#pragma unroll
    for (int b = 0; b < 4; ++b) accG[a][b] = (v4f){0.f, 0.f, 0.f, 0.f};

  __syncthreads();   // implicit vmcnt(0): tile 0 staged (one-time cost)

  int cur = 0;
  for (int it = 0; it < FEAT / BK; ++it) {
    // issue next tile's loads FIRST: they fly during this iter's compute
    if (it + 1 < FEAT / BK) STAGE((it + 1) * BK, lds[cur ^ 1]);

    const char* cb = lds[cur];
#pragma unroll
    for (int s = 0; s < 2; ++s) {
      int psw = s ? psw1 : psw0;
      v8bf afr[8], bz[4];
#pragma unroll
      for (int mi = 0; mi < 8; ++mi) {
        int r = wm * 128 + mi * 16 + lm;
        afr[mi] = *(const v8bf*)(cb + r * 128 + psw);
      }
#pragma unroll
      for (int ni = 0; ni < 4; ++ni) {
        int r = wn * 64 + ni * 16 + lm;
        bz[ni] = *(const v8bf*)(cb + 32768 + r * 128 + psw);
      }
#pragma unroll
      for (int mi = 0; mi < 8; ++mi)
#pragma unroll
        for (int ni = 0; ni < 4; ++ni)
          accG[mi][ni] = __builtin_amdgcn_mfma_f32_16x16x32_bf16(afr[mi], bz[ni], accG[mi][ni], 0, 0, 0);
    }

    __syncthreads();   // RAW (next tile staged) + WAR (this buffer free)
    cur ^= 1;
  }

  // epilogue: C/D col = lane&15 (-> j), row = q*4+reg (-> i);
  // h = ZUT[a_j][i] gathered float4 (i consecutive over reg)
  float tsum = 0.f;
#pragma unroll
  for (int ni = 0; ni < 4; ++ni) {
    int jl = wn * 64 + ni * 16 + lm;
    float sqj = s_sqj[jl];
    float hdj = s_hdj[jl];
    int aj = s_agej[jl];
    int ac = aj < 0 ? 0 : (aj > NUM_AGES - 1 ? NUM_AGES - 1 : aj);
    const float* zrow = zut + (size_t)ac * BATCH + i0;
#pragma unroll
    for (int mi = 0; mi < 8; ++mi) {
      int ilb = wm * 128 + mi * 16 + q * 4;
      float4 h4 = *(const float4*)(zrow + ilb);
      float hh[4] = {h4.x, h4.y, h4.z, h4.w};
#pragma unroll
      for (int r = 0; r < 4; ++r) {
        int il = ilb + r;
        float g = accG[mi][ni][r];
        float d2 = fmaxf(s_sqi[il] + sqj - 2.0f * g, 1e-12f);
        float rs = __builtin_amdgcn_rsqf(d2);
        float arg = (hh[r] - hdj) * INV_T * rs;
        float sp = fmaxf(arg, 0.0f) + __logf(1.0f + __expf(-fabsf(arg)));
        tsum += (s_agei[il] < aj) ? sp : 0.0f;
      }
    }
  }

#pragma unroll
  for (int off = 32; off > 0; off >>= 1) tsum += __shfl_down(tsum, off, 64);
  if (lane == 0) wsum[wv] = tsum;
  __syncthreads();
  if (t == 0) {
    float bs = 0.f;
#pragma unroll
    for (int w = 0; w < 8; ++w) bs += wsum[w];
    atomicAdd(out, bs * INV_NORM);
  }
}

extern "C" void kernel_launch(void* const* d_in, const int* in_sizes, int n_in,
                              void* d_out, int out_size, void* d_ws, size_t ws_size,
                              hipStream_t stream) {
  const float* z = (const float*)d_in[0];
  const int* ages = (const int*)d_in[1];
  const float* proxies = (const float*)d_in[2];
  float* out = (float*)d_out;

  char* ws = (char*)d_ws;
  bf16_t* zb  = (bf16_t*)ws;                                  // 4 MB
  bf16_t* ub  = (bf16_t*)(ws + (size_t)4 * 1024 * 1024);      // 128 KB
  float*  zut = (float*) (ws + (size_t)6 * 1024 * 1024);      // 2 MB (128x4096 f32)
  float*  sq     = (float*)(ws + (size_t)8 * 1024 * 1024);    // 16 KB
  int*    ages_s = (int*)  (ws + (size_t)8 * 1024 * 1024 + 16384);

  prep_kernel<<<528, 512, 0, stream>>>(z, ages, proxies, zb, ub, sq, ages_s, out);
  zu_kernel<<<32, 256, 0, stream>>>(zb, ub, zut);
  pair_kernel<<<NTILES, 512, 0, stream>>>(zb, zut, sq, ages_s, out);
}

// Round 12
// 103.661 us; speedup vs baseline: 1.0012x; 1.0012x over previous
//
#include <hip/hip_runtime.h>
#include <hip/hip_bf16.h>

#define NUM_AGES 100
#define FEAT 512
#define BATCH 4096
#define EPSF 1e-6f
#define INV_T 10.0f
#define INV_NORM (1.0f / ((float)BATCH * (float)(BATCH - 1)))

#define BM 128
#define BN 128
#define BK 64
// kept tiles: by <= bx, bx in [0,32) -> 32*33/2 = 528 = 8*66 (bijective XCD chunking)
#define NTILES 528

typedef __bf16 bf16_t;
typedef __bf16 v8bf __attribute__((ext_vector_type(8)));
typedef float v4f __attribute__((ext_vector_type(4)));

// async global->LDS, 16B per lane; LDS dest is wave-uniform base + lane*16
__device__ __forceinline__ void async16(const void* g, void* l) {
  __builtin_amdgcn_global_load_lds(
      (const __attribute__((address_space(1))) void*)g,
      (__attribute__((address_space(3))) void*)l, 16, 0, 0);
}

// ---------------- kernel 1: prep (samples + U table) — v10, passed -------
// Factorization: w_j depends only on age a_j (100 distinct w vectors);
// H[i,j] = ZU[i, a_j], ZU = Z @ U^T. Blocks 0..511: one wave per sample
// (rank scan via LDS int4, butterfly reduce, pre-swizzled bf16 z store).
// Blocks 512..527: U-table rows (128 padded, pre-swizzled by a&7).
__global__ __launch_bounds__(512) void prep_kernel(
    const float* __restrict__ z, const int* __restrict__ ages,
    const float* __restrict__ proxies,
    bf16_t* __restrict__ zb, bf16_t* __restrict__ ub,
    float* __restrict__ sq, int* __restrict__ ages_s, float* __restrict__ out)
{
  int t = threadIdx.x;
  int wv = t >> 6, lane = t & 63;

  if (blockIdx.x >= 512) {
    int a = (blockIdx.x - 512) * 8 + wv;   // 0..127
    int c0 = lane * 8;
    union { bf16_t h[8]; uint4 u; } uw;
    if (a < NUM_AGES) {
      int an = a + 1 > NUM_AGES - 1 ? NUM_AGES - 1 : a + 1;
      int ap = a - 1 < 0 ? 0 : a - 1;
      const float4* cc4 = (const float4*)(proxies + (size_t)a  * FEAT + c0);
      const float4* cn4 = (const float4*)(proxies + (size_t)an * FEAT + c0);
      const float4* cp4 = (const float4*)(proxies + (size_t)ap * FEAT + c0);
      float df[8], db[8];
      float ff = 0.f, bb = 0.f;
#pragma unroll
      for (int h = 0; h < 2; ++h) {
        float4 c4 = cc4[h], n4 = cn4[h], p4 = cp4[h];
        float cA[4] = {c4.x, c4.y, c4.z, c4.w};
        float nA[4] = {n4.x, n4.y, n4.z, n4.w};
        float pA[4] = {p4.x, p4.y, p4.z, p4.w};
#pragma unroll
        for (int i2 = 0; i2 < 4; ++i2) {
          int i = h * 4 + i2;
          df[i] = nA[i2] - cA[i2];
          db[i] = pA[i2] - cA[i2];
          ff += df[i] * df[i];
          bb += db[i] * db[i];
        }
      }
#pragma unroll
      for (int off = 32; off > 0; off >>= 1) {
        ff += __shfl_xor(ff, off, 64);
        bb += __shfl_xor(bb, off, 64);
      }
      float rf = 1.0f / (sqrtf(ff) + EPSF);
      float rb = 1.0f / (sqrtf(bb) + EPSF);
#pragma unroll
      for (int i = 0; i < 8; ++i)
        uw.h[i] = (bf16_t)(db[i] * rb - df[i] * rf);
    } else {
      uw.u = (uint4){0u, 0u, 0u, 0u};
    }
    int key = a & 7;
    int c2s = (c0 & ~63) | ((((c0 >> 3) & 7) ^ key) << 3);
    *(uint4*)((char*)ub + ((size_t)a * FEAT + c2s) * 2) = uw.u;
    return;
  }

  __shared__ __attribute__((aligned(16))) int sa[BATCH];   // 16 KB
  if (blockIdx.x == 0 && t == 0) out[0] = 0.0f;   // pair accumulates into out

  ((int4*)sa)[t]       = ((const int4*)ages)[t];
  ((int4*)sa)[t + 512] = ((const int4*)ages)[t + 512];
  __syncthreads();

  int j = blockIdx.x * 8 + wv;
  int araw = sa[j];

  int cnt = 0;
  const int4* sa4 = (const int4*)sa;
#pragma unroll
  for (int e = 0; e < 16; ++e) {
    int idx = lane + 64 * e;
    int4 v = sa4[idx];
    int k = idx * 4;
    cnt += (v.x < araw || (v.x == araw && k     < j)) ? 1 : 0;
    cnt += (v.y < araw || (v.y == araw && k + 1 < j)) ? 1 : 0;
    cnt += (v.z < araw || (v.z == araw && k + 2 < j)) ? 1 : 0;
    cnt += (v.w < araw || (v.w == araw && k + 3 < j)) ? 1 : 0;
  }

  int c0 = lane * 8;
  const float4* zr4 = (const float4*)(z + (size_t)j * FEAT + c0);
  float zv[8];
  float zz = 0.f;
#pragma unroll
  for (int h = 0; h < 2; ++h) {
    float4 z4 = zr4[h];
    float zA[4] = {z4.x, z4.y, z4.z, z4.w};
#pragma unroll
    for (int i2 = 0; i2 < 4; ++i2) {
      zv[h * 4 + i2] = zA[i2];
      zz += zA[i2] * zA[i2];
    }
  }
#pragma unroll
  for (int off = 32; off > 0; off >>= 1) {
    zz  += __shfl_xor(zz,  off, 64);
    cnt += __shfl_xor(cnt, off, 64);
  }
  int rank = cnt;
  int key = rank & 7;
  int c2s = (c0 & ~63) | ((((c0 >> 3) & 7) ^ key) << 3);

  union { bf16_t h[8]; uint4 u; } uz;
#pragma unroll
  for (int i = 0; i < 8; ++i) uz.h[i] = (bf16_t)zv[i];
  *(uint4*)((char*)zb + ((size_t)rank * FEAT + c2s) * 2) = uz.u;
  if (lane == 0) {
    sq[rank] = zz;
    ages_s[rank] = araw;
  }
}

// ---------------- kernel 2: ZU = Zsorted @ U^T (32 blocks) — v10, passed -
__global__ __launch_bounds__(256, 3) void zu_kernel(
    const bf16_t* __restrict__ zb, const bf16_t* __restrict__ ub,
    float* __restrict__ zut)
{
  __shared__ __attribute__((aligned(16))) char lds[32768];
  int t = threadIdx.x;
  int wv = t >> 6, lane = t & 63;
  int r0 = blockIdx.x * 128;

  v4f acc[4][4];
#pragma unroll
  for (int a = 0; a < 4; ++a)
#pragma unroll
    for (int b = 0; b < 4; ++b) acc[a][b] = (v4f){0.f, 0.f, 0.f, 0.f};

  int wm = wv >> 1, wn = wv & 1;
  int lm = lane & 15, q = lane >> 4;
  int psw0 = ((q    ) ^ (lm & 7)) * 16;
  int psw1 = ((q + 4) ^ (lm & 7)) * 16;
  int loff = (lane >> 3) * FEAT + (lane & 7) * 8;
  const bf16_t* baseA = zb + (size_t)r0 * FEAT + loff;
  const bf16_t* baseU = ub + loff;

  for (int k0 = 0; k0 < FEAT; k0 += BK) {
#pragma unroll
    for (int c = 0; c < 4; ++c) {
      int chunk = wv * 4 + c;
      async16(baseA + (size_t)chunk * 8 * FEAT + k0, lds + chunk * 1024);
      async16(baseU + (size_t)chunk * 8 * FEAT + k0, lds + 16384 + chunk * 1024);
    }
    __syncthreads();
#pragma unroll
    for (int s = 0; s < 2; ++s) {
      int psw = s ? psw1 : psw0;
      v8bf afr[4], bu[4];
#pragma unroll
      for (int mi = 0; mi < 4; ++mi) {
        int r = wm * 64 + mi * 16 + lm;
        afr[mi] = *(const v8bf*)(lds + r * 128 + psw);
      }
#pragma unroll
      for (int ni = 0; ni < 4; ++ni) {
        int r = wn * 64 + ni * 16 + lm;
        bu[ni] = *(const v8bf*)(lds + 16384 + r * 128 + psw);
      }
#pragma unroll
      for (int mi = 0; mi < 4; ++mi)
#pragma unroll
        for (int ni = 0; ni < 4; ++ni)
          acc[mi][ni] = __builtin_amdgcn_mfma_f32_16x16x32_bf16(afr[mi], bu[ni], acc[mi][ni], 0, 0, 0);
    }
    __syncthreads();
  }

#pragma unroll
  for (int ni = 0; ni < 4; ++ni) {
    int age = wn * 64 + ni * 16 + lm;
#pragma unroll
    for (int mi = 0; mi < 4; ++mi) {
      int rb0 = r0 + wm * 64 + mi * 16 + q * 4;
      *(v4f*)(zut + (size_t)age * BATCH + rb0) = acc[mi][ni];
    }
  }
}

// ---------------- kernel 3: pairwise G-GEMM (v12: NO LDS staging) --------
// Diagnosis across v5..v11: pair invariant ~40-46us while staged bytes fell
// 270->70MB and schedules varied -> per-CU LATENCY-bound on the barrier-
// coupled, depth-1 global_load_lds path (~32-64 loads x 128B in flight /
// ~600cy L3 latency ~= 7-10 B/cyc/CU; 512KB/CU -> ~21us floor + 16 drains).
// Fix per guide Common-mistake #7 ("LDS-staging data that L2-fits is pure
// overhead", m169 +26%): zb is 4MB = L2/L3-resident. Read MFMA fragments
// DIRECTLY global->VGPR. The pre-swizzle granule is k0-independent
// (k0 % 64 == 0), so addr = rowbase + k0*2B + psw{s}: the fully-unrolled
// K-loop is 128 independent 16B loads + 256 MFMAs per wave with NO
// barriers, NO LDS, NO vmcnt(0) -- compiler pipelines loads deeply (ILP)
// and (256,3) gives 12 waves/CU (TLP). 2x panel-read redundancy (2 waves
// share each strip) lands on warm L2/L3 (34.5 TB/s >> our use).
// Geometry: v10's proven 528-tile 128^2 XCD-chunked triangle.
__global__ __launch_bounds__(256, 3) void pair_kernel(
    const bf16_t* __restrict__ zb, const float* __restrict__ zut,
    const float* __restrict__ sq, const int* __restrict__ ages,
    float* __restrict__ out)
{
  __shared__ float s_sqi[BM];
  __shared__ int   s_agei[BM];
  __shared__ float s_sqj[BN];
  __shared__ float s_hdj[BN];
  __shared__ int   s_agej[BN];
  __shared__ float wsum[4];

  int t = threadIdx.x;
  int wv = t >> 6, lane = t & 63;

  // ---- tile decode: XCD chunk + column-major triangle (by <= bx) ----
  int id = (blockIdx.x & 7) * (NTILES / 8) + (blockIdx.x >> 3);
  int bx = 0, rem = id;
  while (rem >= bx + 1) { rem -= bx + 1; ++bx; }
  int by = rem;
  int i0 = by * BM, j0 = bx * BN;

  if (t < BM) {
    s_sqi[t] = sq[i0 + t];
    s_agei[t] = ages[i0 + t];
  } else {
    int u = t - BM;
    int raw = ages[j0 + u];
    int ac = raw < 0 ? 0 : (raw > NUM_AGES - 1 ? NUM_AGES - 1 : raw);
    s_sqj[u] = sq[j0 + u];
    s_agej[u] = raw;
    s_hdj[u] = zut[(size_t)ac * BATCH + j0 + u];
  }
  __syncthreads();   // aux visible to epilogue (no K-loop barriers anymore)

  v4f accG[4][4];
#pragma unroll
  for (int a = 0; a < 4; ++a)
#pragma unroll
    for (int b = 0; b < 4; ++b) accG[a][b] = (v4f){0.f, 0.f, 0.f, 0.f};

  int wm = wv >> 1, wn = wv & 1;        // wave grid 2x2: 64 rows x 64 cols
  int lm = lane & 15, q = lane >> 4;
  // swizzled granule byte offsets (k0-independent: k0 % 64 == 0)
  int psw0 = ((q    ) ^ (lm & 7)) * 16;
  int psw1 = ((q + 4) ^ (lm & 7)) * 16;

  // per-lane fragment row base pointers (bytes)
  const char* arow[4];
  const char* brow[4];
#pragma unroll
  for (int mi = 0; mi < 4; ++mi) {
    int r = i0 + wm * 64 + mi * 16 + lm;
    arow[mi] = (const char*)zb + (size_t)r * FEAT * 2;
  }
#pragma unroll
  for (int ni = 0; ni < 4; ++ni) {
    int r = j0 + wn * 64 + ni * 16 + lm;
    brow[ni] = (const char*)zb + (size_t)r * FEAT * 2;
  }

#pragma unroll
  for (int k0 = 0; k0 < FEAT; k0 += BK) {
#pragma unroll
    for (int s = 0; s < 2; ++s) {
      int off = k0 * 2 + (s ? psw1 : psw0);   // byte offset within row
      v8bf afr[4], bz[4];
#pragma unroll
      for (int mi = 0; mi < 4; ++mi)
        afr[mi] = *(const v8bf*)(arow[mi] + off);
#pragma unroll
      for (int ni = 0; ni < 4; ++ni)
        bz[ni] = *(const v8bf*)(brow[ni] + off);
#pragma unroll
      for (int mi = 0; mi < 4; ++mi)
#pragma unroll
        for (int ni = 0; ni < 4; ++ni)
          accG[mi][ni] = __builtin_amdgcn_mfma_f32_16x16x32_bf16(afr[mi], bz[ni], accG[mi][ni], 0, 0, 0);
    }
  }

  // epilogue: C/D col = lane&15 (-> j), row = q*4+reg (-> i);
  // h = ZUT[a_j][i] gathered float4 (i consecutive over reg)
  float tsum = 0.f;
#pragma unroll
  for (int ni = 0; ni < 4; ++ni) {
    int jl = wn * 64 + ni * 16 + lm;
    float sqj = s_sqj[jl];
    float hdj = s_hdj[jl];
    int aj = s_agej[jl];
    int ac = aj < 0 ? 0 : (aj > NUM_AGES - 1 ? NUM_AGES - 1 : aj);
    const float* zrow = zut + (size_t)ac * BATCH + i0;
#pragma unroll
    for (int mi = 0; mi < 4; ++mi) {
      int ilb = wm * 64 + mi * 16 + q * 4;
      float4 h4 = *(const float4*)(zrow + ilb);
      float hh[4] = {h4.x, h4.y, h4.z, h4.w};
#pragma unroll
      for (int r = 0; r < 4; ++r) {
        int il = ilb + r;
        float g = accG[mi][ni][r];
        float d2 = fmaxf(s_sqi[il] + sqj - 2.0f * g, 1e-12f);
        float rs = __builtin_amdgcn_rsqf(d2);
        float arg = (hh[r] - hdj) * INV_T * rs;
        float sp = fmaxf(arg, 0.0f) + __logf(1.0f + __expf(-fabsf(arg)));
        tsum += (s_agei[il] < aj) ? sp : 0.0f;
      }
    }
  }

#pragma unroll
  for (int off = 32; off > 0; off >>= 1) tsum += __shfl_down(tsum, off, 64);
  if (lane == 0) wsum[wv] = tsum;
  __syncthreads();
  if (t == 0)
    atomicAdd(out, (wsum[0] + wsum[1] + wsum[2] + wsum[3]) * INV_NORM);
}

extern "C" void kernel_launch(void* const* d_in, const int* in_sizes, int n_in,
                              void* d_out, int out_size, void* d_ws, size_t ws_size,
                              hipStream_t stream) {
  const float* z = (const float*)d_in[0];
  const int* ages = (const int*)d_in[1];
  const float* proxies = (const float*)d_in[2];
  float* out = (float*)d_out;

  char* ws = (char*)d_ws;
  bf16_t* zb  = (bf16_t*)ws;                                  // 4 MB
  bf16_t* ub  = (bf16_t*)(ws + (size_t)4 * 1024 * 1024);      // 128 KB
  float*  zut = (float*) (ws + (size_t)6 * 1024 * 1024);      // 2 MB (128x4096 f32)
  float*  sq     = (float*)(ws + (size_t)8 * 1024 * 1024);    // 16 KB
  int*    ages_s = (int*)  (ws + (size_t)8 * 1024 * 1024 + 16384);

  prep_kernel<<<528, 512, 0, stream>>>(z, ages, proxies, zb, ub, sq, ages_s, out);
  zu_kernel<<<32, 256, 0, stream>>>(zb, ub, zut);
  pair_kernel<<<NTILES, 256, 0, stream>>>(zb, zut, sq, ages_s, out);
}

// Round 13
// 98.252 us; speedup vs baseline: 1.0563x; 1.0551x over previous
//
#include <hip/hip_runtime.h>
#include <hip/hip_bf16.h>

#define NUM_AGES 100
#define FEAT 512
#define BATCH 4096
#define EPSF 1e-6f
#define INV_T 10.0f
#define INV_NORM (1.0f / ((float)BATCH * (float)(BATCH - 1)))

#define BM 128
#define BN 128
#define BK 64
// kept tiles: by <= bx, bx in [0,32) -> 32*33/2 = 528 = 8*66 (bijective XCD chunking)
#define NTILES 528

typedef __bf16 bf16_t;
typedef __bf16 v8bf __attribute__((ext_vector_type(8)));
typedef float v4f __attribute__((ext_vector_type(4)));

// async global->LDS, 16B per lane; LDS dest is wave-uniform base + lane*16
__device__ __forceinline__ void async16(const void* g, void* l) {
  __builtin_amdgcn_global_load_lds(
      (const __attribute__((address_space(1))) void*)g,
      (__attribute__((address_space(3))) void*)l, 16, 0, 0);
}

// ---------------- kernel 1: prep (samples + U table) — v10, passed -------
// Factorization: w_j depends only on age a_j (100 distinct w vectors);
// H[i,j] = ZU[i, a_j], ZU = Z @ U^T. Blocks 0..511: one wave per sample
// (rank scan via LDS int4, butterfly reduce, pre-swizzled bf16 z store).
// Blocks 512..527: U-table rows (128 padded, pre-swizzled by a&7).
__global__ __launch_bounds__(512) void prep_kernel(
    const float* __restrict__ z, const int* __restrict__ ages,
    const float* __restrict__ proxies,
    bf16_t* __restrict__ zb, bf16_t* __restrict__ ub,
    float* __restrict__ sq, int* __restrict__ ages_s, float* __restrict__ out)
{
  int t = threadIdx.x;
  int wv = t >> 6, lane = t & 63;

  if (blockIdx.x >= 512) {
    int a = (blockIdx.x - 512) * 8 + wv;   // 0..127
    int c0 = lane * 8;
    union { bf16_t h[8]; uint4 u; } uw;
    if (a < NUM_AGES) {
      int an = a + 1 > NUM_AGES - 1 ? NUM_AGES - 1 : a + 1;
      int ap = a - 1 < 0 ? 0 : a - 1;
      const float4* cc4 = (const float4*)(proxies + (size_t)a  * FEAT + c0);
      const float4* cn4 = (const float4*)(proxies + (size_t)an * FEAT + c0);
      const float4* cp4 = (const float4*)(proxies + (size_t)ap * FEAT + c0);
      float df[8], db[8];
      float ff = 0.f, bb = 0.f;
#pragma unroll
      for (int h = 0; h < 2; ++h) {
        float4 c4 = cc4[h], n4 = cn4[h], p4 = cp4[h];
        float cA[4] = {c4.x, c4.y, c4.z, c4.w};
        float nA[4] = {n4.x, n4.y, n4.z, n4.w};
        float pA[4] = {p4.x, p4.y, p4.z, p4.w};
#pragma unroll
        for (int i2 = 0; i2 < 4; ++i2) {
          int i = h * 4 + i2;
          df[i] = nA[i2] - cA[i2];
          db[i] = pA[i2] - cA[i2];
          ff += df[i] * df[i];
          bb += db[i] * db[i];
        }
      }
#pragma unroll
      for (int off = 32; off > 0; off >>= 1) {
        ff += __shfl_xor(ff, off, 64);
        bb += __shfl_xor(bb, off, 64);
      }
      float rf = 1.0f / (sqrtf(ff) + EPSF);
      float rb = 1.0f / (sqrtf(bb) + EPSF);
#pragma unroll
      for (int i = 0; i < 8; ++i)
        uw.h[i] = (bf16_t)(db[i] * rb - df[i] * rf);
    } else {
      uw.u = (uint4){0u, 0u, 0u, 0u};
    }
    int key = a & 7;
    int c2s = (c0 & ~63) | ((((c0 >> 3) & 7) ^ key) << 3);
    *(uint4*)((char*)ub + ((size_t)a * FEAT + c2s) * 2) = uw.u;
    return;
  }

  __shared__ __attribute__((aligned(16))) int sa[BATCH];   // 16 KB
  if (blockIdx.x == 0 && t == 0) out[0] = 0.0f;   // pair accumulates into out

  ((int4*)sa)[t]       = ((const int4*)ages)[t];
  ((int4*)sa)[t + 512] = ((const int4*)ages)[t + 512];
  __syncthreads();

  int j = blockIdx.x * 8 + wv;
  int araw = sa[j];

  int cnt = 0;
  const int4* sa4 = (const int4*)sa;
#pragma unroll
  for (int e = 0; e < 16; ++e) {
    int idx = lane + 64 * e;
    int4 v = sa4[idx];
    int k = idx * 4;
    cnt += (v.x < araw || (v.x == araw && k     < j)) ? 1 : 0;
    cnt += (v.y < araw || (v.y == araw && k + 1 < j)) ? 1 : 0;
    cnt += (v.z < araw || (v.z == araw && k + 2 < j)) ? 1 : 0;
    cnt += (v.w < araw || (v.w == araw && k + 3 < j)) ? 1 : 0;
  }

  int c0 = lane * 8;
  const float4* zr4 = (const float4*)(z + (size_t)j * FEAT + c0);
  float zv[8];
  float zz = 0.f;
#pragma unroll
  for (int h = 0; h < 2; ++h) {
    float4 z4 = zr4[h];
    float zA[4] = {z4.x, z4.y, z4.z, z4.w};
#pragma unroll
    for (int i2 = 0; i2 < 4; ++i2) {
      zv[h * 4 + i2] = zA[i2];
      zz += zA[i2] * zA[i2];
    }
  }
#pragma unroll
  for (int off = 32; off > 0; off >>= 1) {
    zz  += __shfl_xor(zz,  off, 64);
    cnt += __shfl_xor(cnt, off, 64);
  }
  int rank = cnt;
  int key = rank & 7;
  int c2s = (c0 & ~63) | ((((c0 >> 3) & 7) ^ key) << 3);

  union { bf16_t h[8]; uint4 u; } uz;
#pragma unroll
  for (int i = 0; i < 8; ++i) uz.h[i] = (bf16_t)zv[i];
  *(uint4*)((char*)zb + ((size_t)rank * FEAT + c2s) * 2) = uz.u;
  if (lane == 0) {
    sq[rank] = zz;
    ages_s[rank] = araw;
  }
}

// ---------------- kernel 2: ZU = Zsorted @ U^T (32 blocks) — v10, passed -
__global__ __launch_bounds__(256, 3) void zu_kernel(
    const bf16_t* __restrict__ zb, const bf16_t* __restrict__ ub,
    float* __restrict__ zut)
{
  __shared__ __attribute__((aligned(16))) char lds[32768];
  int t = threadIdx.x;
  int wv = t >> 6, lane = t & 63;
  int r0 = blockIdx.x * 128;

  v4f acc[4][4];
#pragma unroll
  for (int a = 0; a < 4; ++a)
#pragma unroll
    for (int b = 0; b < 4; ++b) acc[a][b] = (v4f){0.f, 0.f, 0.f, 0.f};

  int wm = wv >> 1, wn = wv & 1;
  int lm = lane & 15, q = lane >> 4;
  int psw0 = ((q    ) ^ (lm & 7)) * 16;
  int psw1 = ((q + 4) ^ (lm & 7)) * 16;
  int loff = (lane >> 3) * FEAT + (lane & 7) * 8;
  const bf16_t* baseA = zb + (size_t)r0 * FEAT + loff;
  const bf16_t* baseU = ub + loff;

  for (int k0 = 0; k0 < FEAT; k0 += BK) {
#pragma unroll
    for (int c = 0; c < 4; ++c) {
      int chunk = wv * 4 + c;
      async16(baseA + (size_t)chunk * 8 * FEAT + k0, lds + chunk * 1024);
      async16(baseU + (size_t)chunk * 8 * FEAT + k0, lds + 16384 + chunk * 1024);
    }
    __syncthreads();
#pragma unroll
    for (int s = 0; s < 2; ++s) {
      int psw = s ? psw1 : psw0;
      v8bf afr[4], bu[4];
#pragma unroll
      for (int mi = 0; mi < 4; ++mi) {
        int r = wm * 64 + mi * 16 + lm;
        afr[mi] = *(const v8bf*)(lds + r * 128 + psw);
      }
#pragma unroll
      for (int ni = 0; ni < 4; ++ni) {
        int r = wn * 64 + ni * 16 + lm;
        bu[ni] = *(const v8bf*)(lds + 16384 + r * 128 + psw);
      }
#pragma unroll
      for (int mi = 0; mi < 4; ++mi)
#pragma unroll
        for (int ni = 0; ni < 4; ++ni)
          acc[mi][ni] = __builtin_amdgcn_mfma_f32_16x16x32_bf16(afr[mi], bu[ni], acc[mi][ni], 0, 0, 0);
    }
    __syncthreads();
  }

#pragma unroll
  for (int ni = 0; ni < 4; ++ni) {
    int age = wn * 64 + ni * 16 + lm;
#pragma unroll
    for (int mi = 0; mi < 4; ++mi) {
      int rb0 = r0 + wm * 64 + mi * 16 + q * 4;
      *(v4f*)(zut + (size_t)age * BATCH + rb0) = acc[mi][ni];
    }
  }
}

// ---------------- kernel 3: pairwise G-GEMM (v13 = v10 + 4 blocks/CU) ----
// Model fitted across v5..v12: pair time tracks per-CU read bytes at a
// fixed ~15-25 GB/s/CU -> outstanding-miss-capacity latency limit (Little:
// ~64 in-flight x 128B / ~600cy ~= 12 B/cy/CU). Aggregate BW (v10/v11) and
// barrier structure (v6/v12) both refuted as primary. The untouched lever:
// waves/CU issuing loads. v10 ran 3 blocks/CU; LDS 35KB allows 4.
// ONE change vs v10: launch_bounds(256,3) -> (256,4): 16 waves/CU,
// +33% outstanding capacity. Register check (v4 spill lesson): cap 128 =
// 64 AGPR acc + ~64 VGPR -- exactly the budget r8's pair PROVED fits
// (VGPR_Count 64 + 64 AGPR at cap 128, WRITE_SIZE 16.5KB, no spill).
// Everything else byte-identical to v10 (best measured: 96.7 total).
__global__ __launch_bounds__(256, 4) void pair_kernel(
    const bf16_t* __restrict__ zb, const float* __restrict__ zut,
    const float* __restrict__ sq, const int* __restrict__ ages,
    float* __restrict__ out)
{
  // A: 128x64 bf16 = 16384 B | Z: 128x64 bf16 = 16384 B
  __shared__ __attribute__((aligned(16))) char lds[32768];
  __shared__ float s_sqi[BM];
  __shared__ int   s_agei[BM];
  __shared__ float s_sqj[BN];
  __shared__ float s_hdj[BN];
  __shared__ int   s_agej[BN];
  __shared__ float wsum[4];

  int t = threadIdx.x;
  int wv = t >> 6, lane = t & 63;

  // ---- tile decode: XCD chunk + column-major triangle (by <= bx) ----
  int id = (blockIdx.x & 7) * (NTILES / 8) + (blockIdx.x >> 3);
  int bx = 0, rem = id;
  while (rem >= bx + 1) { rem -= bx + 1; ++bx; }
  int by = rem;
  int i0 = by * BM, j0 = bx * BN;

  if (t < BM) {
    s_sqi[t] = sq[i0 + t];
    s_agei[t] = ages[i0 + t];
  } else {
    int u = t - BM;
    int raw = ages[j0 + u];
    int ac = raw < 0 ? 0 : (raw > NUM_AGES - 1 ? NUM_AGES - 1 : raw);
    s_sqj[u] = sq[j0 + u];
    s_agej[u] = raw;
    s_hdj[u] = zut[(size_t)ac * BATCH + j0 + u];
  }

  v4f accG[4][4];
#pragma unroll
  for (int a = 0; a < 4; ++a)
#pragma unroll
    for (int b = 0; b < 4; ++b) accG[a][b] = (v4f){0.f, 0.f, 0.f, 0.f};

  int wm = wv >> 1, wn = wv & 1;        // wave grid 2x2: 64 rows x 64 cols
  int lm = lane & 15, q = lane >> 4;
  int psw0 = ((q    ) ^ (lm & 7)) * 16;
  int psw1 = ((q + 4) ^ (lm & 7)) * 16;

  int loff = (lane >> 3) * FEAT + (lane & 7) * 8;
  const bf16_t* baseA = zb + (size_t)i0 * FEAT + loff;
  const bf16_t* baseZ = zb + (size_t)j0 * FEAT + loff;

  for (int k0 = 0; k0 < FEAT; k0 += BK) {
#pragma unroll
    for (int c = 0; c < 4; ++c) {
      int chunk = wv * 4 + c;
      async16(baseA + (size_t)chunk * 8 * FEAT + k0, lds + chunk * 1024);
      async16(baseZ + (size_t)chunk * 8 * FEAT + k0, lds + 16384 + chunk * 1024);
    }
    __syncthreads();   // implicit vmcnt(0): tile staged

#pragma unroll
    for (int s = 0; s < 2; ++s) {
      int psw = s ? psw1 : psw0;
      v8bf afr[4], bz[4];
#pragma unroll
      for (int mi = 0; mi < 4; ++mi) {
        int r = wm * 64 + mi * 16 + lm;
        afr[mi] = *(const v8bf*)(lds + r * 128 + psw);
      }
#pragma unroll
      for (int ni = 0; ni < 4; ++ni) {
        int r = wn * 64 + ni * 16 + lm;
        bz[ni] = *(const v8bf*)(lds + 16384 + r * 128 + psw);
      }
#pragma unroll
      for (int mi = 0; mi < 4; ++mi)
#pragma unroll
        for (int ni = 0; ni < 4; ++ni)
          accG[mi][ni] = __builtin_amdgcn_mfma_f32_16x16x32_bf16(afr[mi], bz[ni], accG[mi][ni], 0, 0, 0);
    }
    __syncthreads();   // WAR before next staging
  }

  // epilogue: C/D col = lane&15 (-> j), row = q*4+reg (-> i);
  // h = ZUT[a_j][i] gathered float4 (i consecutive over reg)
  float tsum = 0.f;
#pragma unroll
  for (int ni = 0; ni < 4; ++ni) {
    int jl = wn * 64 + ni * 16 + lm;
    float sqj = s_sqj[jl];
    float hdj = s_hdj[jl];
    int aj = s_agej[jl];
    int ac = aj < 0 ? 0 : (aj > NUM_AGES - 1 ? NUM_AGES - 1 : aj);
    const float* zrow = zut + (size_t)ac * BATCH + i0;
#pragma unroll
    for (int mi = 0; mi < 4; ++mi) {
      int ilb = wm * 64 + mi * 16 + q * 4;
      float4 h4 = *(const float4*)(zrow + ilb);
      float hh[4] = {h4.x, h4.y, h4.z, h4.w};
#pragma unroll
      for (int r = 0; r < 4; ++r) {
        int il = ilb + r;
        float g = accG[mi][ni][r];
        float d2 = fmaxf(s_sqi[il] + sqj - 2.0f * g, 1e-12f);
        float rs = __builtin_amdgcn_rsqf(d2);
        float arg = (hh[r] - hdj) * INV_T * rs;
        float sp = fmaxf(arg, 0.0f) + __logf(1.0f + __expf(-fabsf(arg)));
        tsum += (s_agei[il] < aj) ? sp : 0.0f;
      }
    }
  }

#pragma unroll
  for (int off = 32; off > 0; off >>= 1) tsum += __shfl_down(tsum, off, 64);
  if (lane == 0) wsum[wv] = tsum;
  __syncthreads();
  if (t == 0)
    atomicAdd(out, (wsum[0] + wsum[1] + wsum[2] + wsum[3]) * INV_NORM);
}

extern "C" void kernel_launch(void* const* d_in, const int* in_sizes, int n_in,
                              void* d_out, int out_size, void* d_ws, size_t ws_size,
                              hipStream_t stream) {
  const float* z = (const float*)d_in[0];
  const int* ages = (const int*)d_in[1];
  const float* proxies = (const float*)d_in[2];
  float* out = (float*)d_out;

  char* ws = (char*)d_ws;
  bf16_t* zb  = (bf16_t*)ws;                                  // 4 MB
  bf16_t* ub  = (bf16_t*)(ws + (size_t)4 * 1024 * 1024);      // 128 KB
  float*  zut = (float*) (ws + (size_t)6 * 1024 * 1024);      // 2 MB (128x4096 f32)
  float*  sq     = (float*)(ws + (size_t)8 * 1024 * 1024);    // 16 KB
  int*    ages_s = (int*)  (ws + (size_t)8 * 1024 * 1024 + 16384);

  prep_kernel<<<528, 512, 0, stream>>>(z, ages, proxies, zb, ub, sq, ages_s, out);
  zu_kernel<<<32, 256, 0, stream>>>(zb, ub, zut);
  pair_kernel<<<NTILES, 256, 0, stream>>>(zb, zut, sq, ages_s, out);
}